// Round 18
// baseline (313.340 us; speedup 1.0000x reference)
//
#include <hip/hip_runtime.h>
#include <math.h>

// SoftclDiceLoss on (B,C,D,H,W) = (2,1,64,256,256) float32.
// R18 = R17's launch structure (prep folded away, 6 launches) but with THREE
// SEPARATE plain __global__ kernels to avoid rule-#19 template-instantiation
// codegen cross-talk (R17's middle dispatches regressed 87->113us despite an
// "identical" path):
//   skel_first_kernel : register staging + runtime wave-uniform mode functor
//                       (1: a*mask, 2: sigmoid(a)*mask), lgkm-only barriers.
//   skel_mid_kernel   : R16's proven path VERBATIM (DMA global_load_lds
//                       staging, v0/v2 counted-drain barriers, xc-dedup).
//   skel_final_kernel : R16's FINAL path + runtime mode functor on the two
//                       'other' loads (pred/tgt computed on the fly).
// Shared geometry (champion R16): CD=16, grid 512, x ring-4 padded planes,
// srm ring-2, ONE barrier per segment, merged chains, XCD swizzle.

constexpr int Bn = 2;
constexpr int D  = 64;
constexpr int H  = 256;
constexpr int W  = 256;
constexpr int HW = H * W;           // 65536
constexpr int NV = Bn * D * H * W;  // 8388608

constexpr int CD  = 16;             // D-chunk per block
constexpr int XSF = 76;             // x LDS row stride (19 quads, odd)
constexpr int XPQ = 768;            // padded plane size in quads (12 x 64)
constexpr int RSF = 68;             // rowmax LDS row stride (17 quads, odd)

__device__ __forceinline__ void seg_barrier_v0() {
    asm volatile("s_waitcnt vmcnt(0) lgkmcnt(0)" ::: "memory");
    __builtin_amdgcn_s_barrier();
    asm volatile("" ::: "memory");
}
__device__ __forceinline__ void seg_barrier_v2() {
    asm volatile("s_waitcnt vmcnt(2) lgkmcnt(0)" ::: "memory");
    __builtin_amdgcn_s_barrier();
    asm volatile("" ::: "memory");
}
__device__ __forceinline__ void seg_barrier_lgkm() {
    asm volatile("s_waitcnt lgkmcnt(0)" ::: "memory");
    __builtin_amdgcn_s_barrier();
    asm volatile("" ::: "memory");
}

__device__ __forceinline__ float4 vmin4(float4 a, float4 b) {
    return make_float4(fminf(a.x,b.x), fminf(a.y,b.y), fminf(a.z,b.z), fminf(a.w,b.w));
}
__device__ __forceinline__ float4 vmax4(float4 a, float4 b) {
    return make_float4(fmaxf(a.x,b.x), fmaxf(a.y,b.y), fmaxf(a.z,b.z), fmaxf(a.w,b.w));
}
__device__ __forceinline__ float4 sh1(float4 a, float4 b) { return make_float4(a.y,a.z,a.w,b.x); }
__device__ __forceinline__ float4 sh3(float4 a, float4 b) { return make_float4(a.w,b.x,b.y,b.z); }

// mode 1: a*m ; mode 2: sigmoid(a)*m   (mode is wave-uniform runtime)
__device__ __forceinline__ float4 apply_mode(float4 a, const float* __restrict__ pm,
                                             long ix, int mode) {
    if (mode == 2) {
        a.x = 1.0f / (1.0f + expf(-a.x));
        a.y = 1.0f / (1.0f + expf(-a.y));
        a.z = 1.0f / (1.0f + expf(-a.z));
        a.w = 1.0f / (1.0f + expf(-a.w));
    }
    float4 m = *(const float4*)(pm + ix);
    a.x *= m.x; a.y *= m.y; a.z *= m.z; a.w *= m.w;
    return a;
}

// ---------- shared geometry decode ----------
struct Geo {
    int t, w0, h0, gd0, b, r, k, wv, lane;
    int offe[3]; bool okl[3];
};
__device__ __forceinline__ Geo decode_geo() {
    Geo g;
    int cpx = gridDim.x >> 3;
    int hwb = blockIdx.x;
    int bx  = (hwb & 7) * cpx + (hwb >> 3);
    g.t   = bx >> 8;
    int bt  = bx & 255;
    g.w0  = (bt & 3) * 64;
    g.h0  = ((bt >> 2) & 7) * 32;
    g.gd0 = ((bt >> 5) & 3) * CD;
    g.b   = (bt >> 7) & 1;
    int tid = threadIdx.x;
    g.r = tid >> 3; g.k = tid & 7; g.wv = tid >> 6; g.lane = tid & 63;
    for (int i = 0; i < 3; ++i) {
        int c = g.wv + 4 * i;
        int j = 64 * c + g.lane;
        int row = j / 19;
        int q = j - 19 * row;
        int gh = g.h0 - 2 + row;
        int gw = g.w0 - 4 + 4 * q;
        g.okl[i] = (q < 18) && (row < 36) &&
                   ((unsigned)gh < (unsigned)H) && ((unsigned)gw < (unsigned)W);
        g.offe[i] = gh * W + gw;
    }
    return g;
}

// ---------- compute-stage macro body (identical across the 3 kernels) ----------
// Implemented as a macro-free inline via lambdas would risk codegen drift; we
// duplicate the body literally in each kernel (mechanical copy of R16).

// ======================= 1) FIRST (fused prep, reg staging) ==================
__global__ __launch_bounds__(256) void skel_first_kernel(
        const float* __restrict__ iA0, const float* __restrict__ iM0, int im0,
        float* __restrict__ out0,
        const float* __restrict__ iA1, const float* __restrict__ iM1, int im1,
        float* __restrict__ out1) {
    __shared__ float sx[4][XPQ * 4];
    __shared__ float srm[2][34 * RSF];

    Geo g = decode_geo();
    const float* iA = g.t ? iA1 : iA0;
    const float* iM = g.t ? iM1 : iM0;
    const int    im = g.t ? im1 : im0;
    float*     xout = g.t ? out1 : out0;

    int r = g.r, k = g.k, wv = g.wv, lane = g.lane;
    int w0 = g.w0, h0 = g.h0, gd0 = g.gd0;
    int tid = threadIdx.x;

    long base = (long)g.b * (D * HW);
    const float* xbA = iA + base;
    const float* xbM = iM + base;
    float*       ob  = xout + base;

    const float4 INF4  = make_float4( INFINITY,  INFINITY,  INFINITY,  INFINITY);
    const float4 NINF4 = make_float4(-INFINITY, -INFINITY, -INFINITY, -INFINITY);

    float4 Pa, Pb, Pc;
    auto issue_r = [&](int p) {
        if (p < 0 || p >= D) { Pa = Pb = Pc = INF4; return; }
        const float* pA = xbA + (long)p * HW;
        const float* pM = xbM + (long)p * HW;
        float4 v[3];
        #pragma unroll
        for (int i = 0; i < 3; ++i) {
            v[i] = g.okl[i] ? apply_mode(*(const float4*)(pA + g.offe[i]), pM, g.offe[i], im)
                            : INF4;
        }
        Pa = v[0]; Pb = v[1]; Pc = v[2];
    };
    auto commit_r = [&](int p, float4 va, float4 vb, float4 vc) {
        float* slot = sx[(p + 4) & 3];
        *(float4*)&slot[(wv + 0) * 256 + 4 * lane] = va;
        *(float4*)&slot[(wv + 4) * 256 + 4 * lane] = vb;
        *(float4*)&slot[(wv + 8) * 256 + 4 * lane] = vc;
    };

    issue_r(gd0 - 2); commit_r(gd0 - 2, Pa, Pb, Pc);
    issue_r(gd0 - 1); commit_r(gd0 - 1, Pa, Pb, Pc);
    issue_r(gd0);     commit_r(gd0,     Pa, Pb, Pc);
    issue_r(gd0 + 1);
    __syncthreads();

    float4 h1lo=NINF4, h1hi=NINF4, h2lo=NINF4, h2hi=NINF4;
    float4 p1lo=NINF4, p1hi=NINF4, p2lo=NINF4, p2hi=NINF4;
    float4 rmplo=NINF4, rmphi=NINF4;
    float4 xplo=INF4, xphi=INF4;

    for (int s = gd0 - 1; s <= gd0 + CD + 1; ++s) {
        float4 Ta = Pa, Tb = Pb, Tc = Pc;
        if (s + 3 <= gd0 + CD + 1) issue_r(s + 3);
        if (s + 2 <= gd0 + CD + 1) commit_r(s + 2, Ta, Tb, Tc);

        bool sv = (s >= 0 && s < D && s <= gd0 + CD);
        float4 lo = NINF4, hi = NINF4, rmlo = NINF4, rmhi = NINF4;
        float4 vM1 = INF4, vM2 = INF4;
        if (sv) {
            const float* xq = sx[(s + 4) & 3];
            const float* xm = sx[(s + 3) & 3];
            const float* xp = sx[(s + 5) & 3];
            {
                const float* rc  = &xq[(r + 2) * XSF + 8 * k];
                const float* ru  = &xq[(r + 1) * XSF + 8 * k];
                const float* rd  = &xq[(r + 3) * XSF + 8 * k];
                const float* rm_ = &xm[(r + 2) * XSF + 8 * k];
                const float* rp_ = &xp[(r + 2) * XSF + 8 * k];
                float4 X0 = *(const float4*)rc,        X1 = *(const float4*)(rc + 4),
                       X2 = *(const float4*)(rc + 8),  X3 = *(const float4*)(rc + 12);
                float4 U1 = *(const float4*)(ru + 4),  U2 = *(const float4*)(ru + 8);
                float4 Dn1= *(const float4*)(rd + 4),  Dn2= *(const float4*)(rd + 8);
                float4 M1 = *(const float4*)(rm_ + 4), M2 = *(const float4*)(rm_ + 8);
                float4 P1 = *(const float4*)(rp_ + 4), P2 = *(const float4*)(rp_ + 8);
                vM1 = M1; vM2 = M2;
                lo = vmin4(vmin4(sh3(X0, X1), X1), sh1(X1, X2));
                lo = vmin4(lo, vmin4(vmin4(U1, Dn1), vmin4(M1, P1)));
                hi = vmin4(vmin4(sh3(X1, X2), X2), sh1(X2, X3));
                hi = vmin4(hi, vmin4(vmin4(U2, Dn2), vmin4(M2, P2)));
                float eL = __shfl_up(hi.w, 1);
                float eR = __shfl_down(lo.x, 1);
                if (k == 0) {
                    eL = -INFINITY;
                    if (w0 > 0) {
                        float w3 = fminf(fminf(X0.z, X0.w), X1.x);
                        eL = fminf(fminf(w3, fminf(ru[3], rd[3])), fminf(rm_[3], rp_[3]));
                    }
                }
                if (k == 7) {
                    eR = -INFINITY;
                    if (w0 + 64 < W) {
                        float w3 = fminf(fminf(X2.w, X3.x), X3.y);
                        eR = fminf(fminf(w3, fminf(ru[12], rd[12])), fminf(rm_[12], rp_[12]));
                    }
                }
                rmlo = vmax4(vmax4(make_float4(eL, lo.x, lo.y, lo.z), lo),
                             make_float4(lo.y, lo.z, lo.w, hi.x));
                rmhi = vmax4(vmax4(make_float4(lo.w, hi.x, hi.y, hi.z), hi),
                             make_float4(hi.y, hi.z, hi.w, eR));
                float* rw = &srm[s & 1][(r + 1) * RSF + 8 * k];
                *(float4*)rw       = rmlo;
                *(float4*)(rw + 4) = rmhi;
            }
            if (tid < 16) {
                int mr2 = (tid >> 3) ? 33 : 0;
                int k2  = tid & 7;
                int gh2 = h0 - 1 + mr2;
                float4 hlo = NINF4, hhi = NINF4;
                if ((unsigned)gh2 < (unsigned)H) {
                    int xr2 = mr2 + 1;
                    const float* rc  = &xq[xr2 * XSF + 8 * k2];
                    const float* ru  = &xq[(xr2 - 1) * XSF + 8 * k2];
                    const float* rd  = &xq[(xr2 + 1) * XSF + 8 * k2];
                    const float* rm_ = &xm[xr2 * XSF + 8 * k2];
                    const float* rp_ = &xp[xr2 * XSF + 8 * k2];
                    float4 X0 = *(const float4*)rc,        X1 = *(const float4*)(rc + 4),
                           X2 = *(const float4*)(rc + 8),  X3 = *(const float4*)(rc + 12);
                    float4 U1 = *(const float4*)(ru + 4),  U2 = *(const float4*)(ru + 8);
                    float4 Dn1= *(const float4*)(rd + 4),  Dn2= *(const float4*)(rd + 8);
                    float4 M1 = *(const float4*)(rm_ + 4), M2 = *(const float4*)(rm_ + 8);
                    float4 P1 = *(const float4*)(rp_ + 4), P2 = *(const float4*)(rp_ + 8);
                    float4 l2 = vmin4(vmin4(sh3(X0, X1), X1), sh1(X1, X2));
                    l2 = vmin4(l2, vmin4(vmin4(U1, Dn1), vmin4(M1, P1)));
                    float4 g2 = vmin4(vmin4(sh3(X1, X2), X2), sh1(X2, X3));
                    g2 = vmin4(g2, vmin4(vmin4(U2, Dn2), vmin4(M2, P2)));
                    float eL2 = -INFINITY, eR2 = -INFINITY;
                    if (w0 + 8 * k2 - 1 >= 0) {
                        float w3 = fminf(fminf(X0.z, X0.w), X1.x);
                        eL2 = fminf(fminf(w3, fminf(ru[3], rd[3])), fminf(rm_[3], rp_[3]));
                    }
                    if (w0 + 8 * k2 + 8 < W) {
                        float w3 = fminf(fminf(X2.w, X3.x), X3.y);
                        eR2 = fminf(fminf(w3, fminf(ru[12], rd[12])), fminf(rm_[12], rp_[12]));
                    }
                    hlo = vmax4(vmax4(make_float4(eL2, l2.x, l2.y, l2.z), l2),
                                make_float4(l2.y, l2.z, l2.w, g2.x));
                    hhi = vmax4(vmax4(make_float4(l2.w, g2.x, g2.y, g2.z), g2),
                                make_float4(g2.y, g2.z, g2.w, eR2));
                }
                float* hw = &srm[s & 1][mr2 * RSF + 8 * k2];
                *(float4*)hw       = hlo;
                *(float4*)(hw + 4) = hhi;
            }
        }

        int dm = s - 1;
        float4 xclo = INF4, xchi = INF4;
        if (dm >= gd0 && dm <= gd0 + CD - 1) {
            if (sv) { xclo = vM1; xchi = vM2; }
            else {
                const float* xd = sx[(dm + 4) & 3];
                xclo = *(const float4*)&xd[(r + 2) * XSF + 8 * k + 4];
                xchi = *(const float4*)&xd[(r + 2) * XSF + 8 * k + 8];
            }
        }

        float4 hclo = NINF4, hchi = NINF4;
        if (s >= gd0 && dm >= 0 && dm < D) {
            const float* m = srm[dm & 1];
            float4 a0 = *(const float4*)&m[r * RSF + 8 * k];
            float4 a1 = *(const float4*)&m[r * RSF + 8 * k + 4];
            float4 b0 = *(const float4*)&m[(r + 2) * RSF + 8 * k];
            float4 b1 = *(const float4*)&m[(r + 2) * RSF + 8 * k + 4];
            hclo = vmax4(vmax4(a0, rmplo), b0);
            hchi = vmax4(vmax4(a1, rmphi), b1);
        }

        int d = s - 2;
        if (d >= gd0 && d <= gd0 + CD - 1) {
            float4 mxlo = vmax4(h2lo, vmax4(h1lo, hclo));
            float4 mxhi = vmax4(h2hi, vmax4(h1hi, hchi));
            float4 rlo, rhi;
            rlo.x = fmaxf(xplo.x - (mxlo.x - p2lo.x), 0.0f);
            rlo.y = fmaxf(xplo.y - (mxlo.y - p2lo.y), 0.0f);
            rlo.z = fmaxf(xplo.z - (mxlo.z - p2lo.z), 0.0f);
            rlo.w = fmaxf(xplo.w - (mxlo.w - p2lo.w), 0.0f);
            rhi.x = fmaxf(xphi.x - (mxhi.x - p2hi.x), 0.0f);
            rhi.y = fmaxf(xphi.y - (mxhi.y - p2hi.y), 0.0f);
            rhi.z = fmaxf(xphi.z - (mxhi.z - p2hi.z), 0.0f);
            rhi.w = fmaxf(xphi.w - (mxhi.w - p2hi.w), 0.0f);
            long off = (long)d * HW + (h0 + r) * W + (w0 + 8 * k);
            *(float4*)(ob + off)     = rlo;
            *(float4*)(ob + off + 4) = rhi;
        }

        h2lo = h1lo; h2hi = h1hi; h1lo = hclo; h1hi = hchi;
        p2lo = p1lo; p2hi = p1hi; p1lo = lo;   p1hi = hi;
        rmplo = rmlo; rmphi = rmhi;
        xplo = xclo;  xphi = xchi;

        seg_barrier_lgkm();
    }
}

// ======================= 2) MID (R16 path verbatim) ==========================
__global__ __launch_bounds__(256) void skel_mid_kernel(
        const float* __restrict__ in0, float* __restrict__ out0,
        const float* __restrict__ in1, float* __restrict__ out1,
        const float* __restrict__ infbuf) {
    __shared__ float sx[4][XPQ * 4];
    __shared__ float srm[2][34 * RSF];

    Geo g = decode_geo();
    const float* xin  = g.t ? in1  : in0;
    float*       xout = g.t ? out1 : out0;

    int r = g.r, k = g.k, wv = g.wv;
    int w0 = g.w0, h0 = g.h0, gd0 = g.gd0;
    int tid = threadIdx.x;

    const float* xb = xin + g.b * (D * HW);
    float*       ob = xout + g.b * (D * HW);

    const float4 INF4  = make_float4( INFINITY,  INFINITY,  INFINITY,  INFINITY);
    const float4 NINF4 = make_float4(-INFINITY, -INFINITY, -INFINITY, -INFINITY);

    auto issue_g = [&](int p) {
        bool pok = (p >= 0 && p < D);
        const float* pbase = xb + (long)p * HW;
        float* slot = sx[(p + 4) & 3];
        #pragma unroll
        for (int i = 0; i < 3; ++i) {
            const float* src = (pok && g.okl[i]) ? (pbase + g.offe[i]) : infbuf;
            float* dst = slot + (wv + 4 * i) * 256;
            __builtin_amdgcn_global_load_lds(
                (const __attribute__((address_space(1))) void*)src,
                (__attribute__((address_space(3))) void*)dst, 16, 0, 0);
        }
    };

    issue_g(gd0 - 2); issue_g(gd0 - 1); issue_g(gd0); issue_g(gd0 + 1);
    __syncthreads();

    float4 h1lo=NINF4, h1hi=NINF4, h2lo=NINF4, h2hi=NINF4;
    float4 p1lo=NINF4, p1hi=NINF4, p2lo=NINF4, p2hi=NINF4;
    float4 rmplo=NINF4, rmphi=NINF4;
    float4 xplo=INF4, xphi=INF4;

    for (int s = gd0 - 1; s <= gd0 + CD + 1; ++s) {
        if (s >= gd0 && s + 2 <= gd0 + CD + 1) issue_g(s + 2);
        asm volatile("" ::: "memory");

        bool sv = (s >= 0 && s < D && s <= gd0 + CD);
        float4 lo = NINF4, hi = NINF4, rmlo = NINF4, rmhi = NINF4;
        float4 vM1 = INF4, vM2 = INF4;
        if (sv) {
            const float* xq = sx[(s + 4) & 3];
            const float* xm = sx[(s + 3) & 3];
            const float* xp = sx[(s + 5) & 3];
            {
                const float* rc  = &xq[(r + 2) * XSF + 8 * k];
                const float* ru  = &xq[(r + 1) * XSF + 8 * k];
                const float* rd  = &xq[(r + 3) * XSF + 8 * k];
                const float* rm_ = &xm[(r + 2) * XSF + 8 * k];
                const float* rp_ = &xp[(r + 2) * XSF + 8 * k];
                float4 X0 = *(const float4*)rc,        X1 = *(const float4*)(rc + 4),
                       X2 = *(const float4*)(rc + 8),  X3 = *(const float4*)(rc + 12);
                float4 U1 = *(const float4*)(ru + 4),  U2 = *(const float4*)(ru + 8);
                float4 Dn1= *(const float4*)(rd + 4),  Dn2= *(const float4*)(rd + 8);
                float4 M1 = *(const float4*)(rm_ + 4), M2 = *(const float4*)(rm_ + 8);
                float4 P1 = *(const float4*)(rp_ + 4), P2 = *(const float4*)(rp_ + 8);
                vM1 = M1; vM2 = M2;
                lo = vmin4(vmin4(sh3(X0, X1), X1), sh1(X1, X2));
                lo = vmin4(lo, vmin4(vmin4(U1, Dn1), vmin4(M1, P1)));
                hi = vmin4(vmin4(sh3(X1, X2), X2), sh1(X2, X3));
                hi = vmin4(hi, vmin4(vmin4(U2, Dn2), vmin4(M2, P2)));
                float eL = __shfl_up(hi.w, 1);
                float eR = __shfl_down(lo.x, 1);
                if (k == 0) {
                    eL = -INFINITY;
                    if (w0 > 0) {
                        float w3 = fminf(fminf(X0.z, X0.w), X1.x);
                        eL = fminf(fminf(w3, fminf(ru[3], rd[3])), fminf(rm_[3], rp_[3]));
                    }
                }
                if (k == 7) {
                    eR = -INFINITY;
                    if (w0 + 64 < W) {
                        float w3 = fminf(fminf(X2.w, X3.x), X3.y);
                        eR = fminf(fminf(w3, fminf(ru[12], rd[12])), fminf(rm_[12], rp_[12]));
                    }
                }
                rmlo = vmax4(vmax4(make_float4(eL, lo.x, lo.y, lo.z), lo),
                             make_float4(lo.y, lo.z, lo.w, hi.x));
                rmhi = vmax4(vmax4(make_float4(lo.w, hi.x, hi.y, hi.z), hi),
                             make_float4(hi.y, hi.z, hi.w, eR));
                float* rw = &srm[s & 1][(r + 1) * RSF + 8 * k];
                *(float4*)rw       = rmlo;
                *(float4*)(rw + 4) = rmhi;
            }
            if (tid < 16) {
                int mr2 = (tid >> 3) ? 33 : 0;
                int k2  = tid & 7;
                int gh2 = h0 - 1 + mr2;
                float4 hlo = NINF4, hhi = NINF4;
                if ((unsigned)gh2 < (unsigned)H) {
                    int xr2 = mr2 + 1;
                    const float* rc  = &xq[xr2 * XSF + 8 * k2];
                    const float* ru  = &xq[(xr2 - 1) * XSF + 8 * k2];
                    const float* rd  = &xq[(xr2 + 1) * XSF + 8 * k2];
                    const float* rm_ = &xm[xr2 * XSF + 8 * k2];
                    const float* rp_ = &xp[xr2 * XSF + 8 * k2];
                    float4 X0 = *(const float4*)rc,        X1 = *(const float4*)(rc + 4),
                           X2 = *(const float4*)(rc + 8),  X3 = *(const float4*)(rc + 12);
                    float4 U1 = *(const float4*)(ru + 4),  U2 = *(const float4*)(ru + 8);
                    float4 Dn1= *(const float4*)(rd + 4),  Dn2= *(const float4*)(rd + 8);
                    float4 M1 = *(const float4*)(rm_ + 4), M2 = *(const float4*)(rm_ + 8);
                    float4 P1 = *(const float4*)(rp_ + 4), P2 = *(const float4*)(rp_ + 8);
                    float4 l2 = vmin4(vmin4(sh3(X0, X1), X1), sh1(X1, X2));
                    l2 = vmin4(l2, vmin4(vmin4(U1, Dn1), vmin4(M1, P1)));
                    float4 g2 = vmin4(vmin4(sh3(X1, X2), X2), sh1(X2, X3));
                    g2 = vmin4(g2, vmin4(vmin4(U2, Dn2), vmin4(M2, P2)));
                    float eL2 = -INFINITY, eR2 = -INFINITY;
                    if (w0 + 8 * k2 - 1 >= 0) {
                        float w3 = fminf(fminf(X0.z, X0.w), X1.x);
                        eL2 = fminf(fminf(w3, fminf(ru[3], rd[3])), fminf(rm_[3], rp_[3]));
                    }
                    if (w0 + 8 * k2 + 8 < W) {
                        float w3 = fminf(fminf(X2.w, X3.x), X3.y);
                        eR2 = fminf(fminf(w3, fminf(ru[12], rd[12])), fminf(rm_[12], rp_[12]));
                    }
                    hlo = vmax4(vmax4(make_float4(eL2, l2.x, l2.y, l2.z), l2),
                                make_float4(l2.y, l2.z, l2.w, g2.x));
                    hhi = vmax4(vmax4(make_float4(l2.w, g2.x, g2.y, g2.z), g2),
                                make_float4(g2.y, g2.z, g2.w, eR2));
                }
                float* hw = &srm[s & 1][mr2 * RSF + 8 * k2];
                *(float4*)hw       = hlo;
                *(float4*)(hw + 4) = hhi;
            }
        }

        int dm = s - 1;
        float4 xclo = INF4, xchi = INF4;
        if (dm >= gd0 && dm <= gd0 + CD - 1) {
            if (sv) { xclo = vM1; xchi = vM2; }
            else {
                const float* xd = sx[(dm + 4) & 3];
                xclo = *(const float4*)&xd[(r + 2) * XSF + 8 * k + 4];
                xchi = *(const float4*)&xd[(r + 2) * XSF + 8 * k + 8];
            }
        }

        float4 hclo = NINF4, hchi = NINF4;
        if (s >= gd0 && dm >= 0 && dm < D) {
            const float* m = srm[dm & 1];
            float4 a0 = *(const float4*)&m[r * RSF + 8 * k];
            float4 a1 = *(const float4*)&m[r * RSF + 8 * k + 4];
            float4 b0 = *(const float4*)&m[(r + 2) * RSF + 8 * k];
            float4 b1 = *(const float4*)&m[(r + 2) * RSF + 8 * k + 4];
            hclo = vmax4(vmax4(a0, rmplo), b0);
            hchi = vmax4(vmax4(a1, rmphi), b1);
        }

        int d = s - 2;
        if (d >= gd0 && d <= gd0 + CD - 1) {
            float4 mxlo = vmax4(h2lo, vmax4(h1lo, hclo));
            float4 mxhi = vmax4(h2hi, vmax4(h1hi, hchi));
            float4 rlo, rhi;
            rlo.x = fmaxf(xplo.x - (mxlo.x - p2lo.x), 0.0f);
            rlo.y = fmaxf(xplo.y - (mxlo.y - p2lo.y), 0.0f);
            rlo.z = fmaxf(xplo.z - (mxlo.z - p2lo.z), 0.0f);
            rlo.w = fmaxf(xplo.w - (mxlo.w - p2lo.w), 0.0f);
            rhi.x = fmaxf(xphi.x - (mxhi.x - p2hi.x), 0.0f);
            rhi.y = fmaxf(xphi.y - (mxhi.y - p2hi.y), 0.0f);
            rhi.z = fmaxf(xphi.z - (mxhi.z - p2hi.z), 0.0f);
            rhi.w = fmaxf(xphi.w - (mxhi.w - p2hi.w), 0.0f);
            long off = (long)d * HW + (h0 + r) * W + (w0 + 8 * k);
            *(float4*)(ob + off)     = rlo;
            *(float4*)(ob + off + 4) = rhi;
        }

        h2lo = h1lo; h2hi = h1hi; h1lo = hclo; h1hi = hchi;
        p2lo = p1lo; p2hi = p1hi; p1lo = lo;   p1hi = hi;
        rmplo = rmlo; rmphi = rmhi;
        xplo = xclo;  xphi = xchi;

        if (s <= gd0 + 1) seg_barrier_v0();
        else              seg_barrier_v2();
    }
}

// ======================= 3) FINAL (fused reduce, mode on other) ==============
__global__ __launch_bounds__(256) void skel_final_kernel(
        const float* __restrict__ in0,
        const float* __restrict__ oA0, const float* __restrict__ oB0, int om0,
        double* __restrict__ acc0,
        const float* __restrict__ in1,
        const float* __restrict__ oA1, const float* __restrict__ oB1, int om1,
        double* __restrict__ acc1,
        const float* __restrict__ infbuf) {
    __shared__ float sx[4][XPQ * 4];
    __shared__ float srm[2][34 * RSF];

    Geo g = decode_geo();
    const float* xin = g.t ? in1 : in0;
    const float* oA  = g.t ? oA1 : oA0;
    const float* oB  = g.t ? oB1 : oB0;
    const int    om  = g.t ? om1 : om0;
    double*     accp = g.t ? acc1 : acc0;

    int r = g.r, k = g.k, wv = g.wv;
    int w0 = g.w0, h0 = g.h0, gd0 = g.gd0;
    int tid = threadIdx.x;

    long base = (long)g.b * (D * HW);
    const float* xb  = xin + base;
    const float* otA = oA + base;
    const float* otB = oB + base;

    const float4 INF4  = make_float4( INFINITY,  INFINITY,  INFINITY,  INFINITY);
    const float4 NINF4 = make_float4(-INFINITY, -INFINITY, -INFINITY, -INFINITY);

    auto issue_g = [&](int p) {
        bool pok = (p >= 0 && p < D);
        const float* pbase = xb + (long)p * HW;
        float* slot = sx[(p + 4) & 3];
        #pragma unroll
        for (int i = 0; i < 3; ++i) {
            const float* src = (pok && g.okl[i]) ? (pbase + g.offe[i]) : infbuf;
            float* dst = slot + (wv + 4 * i) * 256;
            __builtin_amdgcn_global_load_lds(
                (const __attribute__((address_space(1))) void*)src,
                (__attribute__((address_space(3))) void*)dst, 16, 0, 0);
        }
    };

    issue_g(gd0 - 2); issue_g(gd0 - 1); issue_g(gd0); issue_g(gd0 + 1);
    __syncthreads();

    float4 h1lo=NINF4, h1hi=NINF4, h2lo=NINF4, h2hi=NINF4;
    float4 p1lo=NINF4, p1hi=NINF4, p2lo=NINF4, p2hi=NINF4;
    float4 rmplo=NINF4, rmphi=NINF4;
    float4 xplo=INF4, xphi=INF4;
    double s0 = 0.0, s1 = 0.0;

    for (int s = gd0 - 1; s <= gd0 + CD + 1; ++s) {
        if (s >= gd0 && s + 2 <= gd0 + CD + 1) issue_g(s + 2);
        asm volatile("" ::: "memory");

        bool sv = (s >= 0 && s < D && s <= gd0 + CD);
        float4 lo = NINF4, hi = NINF4, rmlo = NINF4, rmhi = NINF4;
        float4 vM1 = INF4, vM2 = INF4;
        if (sv) {
            const float* xq = sx[(s + 4) & 3];
            const float* xm = sx[(s + 3) & 3];
            const float* xp = sx[(s + 5) & 3];
            {
                const float* rc  = &xq[(r + 2) * XSF + 8 * k];
                const float* ru  = &xq[(r + 1) * XSF + 8 * k];
                const float* rd  = &xq[(r + 3) * XSF + 8 * k];
                const float* rm_ = &xm[(r + 2) * XSF + 8 * k];
                const float* rp_ = &xp[(r + 2) * XSF + 8 * k];
                float4 X0 = *(const float4*)rc,        X1 = *(const float4*)(rc + 4),
                       X2 = *(const float4*)(rc + 8),  X3 = *(const float4*)(rc + 12);
                float4 U1 = *(const float4*)(ru + 4),  U2 = *(const float4*)(ru + 8);
                float4 Dn1= *(const float4*)(rd + 4),  Dn2= *(const float4*)(rd + 8);
                float4 M1 = *(const float4*)(rm_ + 4), M2 = *(const float4*)(rm_ + 8);
                float4 P1 = *(const float4*)(rp_ + 4), P2 = *(const float4*)(rp_ + 8);
                vM1 = M1; vM2 = M2;
                lo = vmin4(vmin4(sh3(X0, X1), X1), sh1(X1, X2));
                lo = vmin4(lo, vmin4(vmin4(U1, Dn1), vmin4(M1, P1)));
                hi = vmin4(vmin4(sh3(X1, X2), X2), sh1(X2, X3));
                hi = vmin4(hi, vmin4(vmin4(U2, Dn2), vmin4(M2, P2)));
                float eL = __shfl_up(hi.w, 1);
                float eR = __shfl_down(lo.x, 1);
                if (k == 0) {
                    eL = -INFINITY;
                    if (w0 > 0) {
                        float w3 = fminf(fminf(X0.z, X0.w), X1.x);
                        eL = fminf(fminf(w3, fminf(ru[3], rd[3])), fminf(rm_[3], rp_[3]));
                    }
                }
                if (k == 7) {
                    eR = -INFINITY;
                    if (w0 + 64 < W) {
                        float w3 = fminf(fminf(X2.w, X3.x), X3.y);
                        eR = fminf(fminf(w3, fminf(ru[12], rd[12])), fminf(rm_[12], rp_[12]));
                    }
                }
                rmlo = vmax4(vmax4(make_float4(eL, lo.x, lo.y, lo.z), lo),
                             make_float4(lo.y, lo.z, lo.w, hi.x));
                rmhi = vmax4(vmax4(make_float4(lo.w, hi.x, hi.y, hi.z), hi),
                             make_float4(hi.y, hi.z, hi.w, eR));
                float* rw = &srm[s & 1][(r + 1) * RSF + 8 * k];
                *(float4*)rw       = rmlo;
                *(float4*)(rw + 4) = rmhi;
            }
            if (tid < 16) {
                int mr2 = (tid >> 3) ? 33 : 0;
                int k2  = tid & 7;
                int gh2 = h0 - 1 + mr2;
                float4 hlo = NINF4, hhi = NINF4;
                if ((unsigned)gh2 < (unsigned)H) {
                    int xr2 = mr2 + 1;
                    const float* rc  = &xq[xr2 * XSF + 8 * k2];
                    const float* ru  = &xq[(xr2 - 1) * XSF + 8 * k2];
                    const float* rd  = &xq[(xr2 + 1) * XSF + 8 * k2];
                    const float* rm_ = &xm[xr2 * XSF + 8 * k2];
                    const float* rp_ = &xp[xr2 * XSF + 8 * k2];
                    float4 X0 = *(const float4*)rc,        X1 = *(const float4*)(rc + 4),
                           X2 = *(const float4*)(rc + 8),  X3 = *(const float4*)(rc + 12);
                    float4 U1 = *(const float4*)(ru + 4),  U2 = *(const float4*)(ru + 8);
                    float4 Dn1= *(const float4*)(rd + 4),  Dn2= *(const float4*)(rd + 8);
                    float4 M1 = *(const float4*)(rm_ + 4), M2 = *(const float4*)(rm_ + 8);
                    float4 P1 = *(const float4*)(rp_ + 4), P2 = *(const float4*)(rp_ + 8);
                    float4 l2 = vmin4(vmin4(sh3(X0, X1), X1), sh1(X1, X2));
                    l2 = vmin4(l2, vmin4(vmin4(U1, Dn1), vmin4(M1, P1)));
                    float4 g2 = vmin4(vmin4(sh3(X1, X2), X2), sh1(X2, X3));
                    g2 = vmin4(g2, vmin4(vmin4(U2, Dn2), vmin4(M2, P2)));
                    float eL2 = -INFINITY, eR2 = -INFINITY;
                    if (w0 + 8 * k2 - 1 >= 0) {
                        float w3 = fminf(fminf(X0.z, X0.w), X1.x);
                        eL2 = fminf(fminf(w3, fminf(ru[3], rd[3])), fminf(rm_[3], rp_[3]));
                    }
                    if (w0 + 8 * k2 + 8 < W) {
                        float w3 = fminf(fminf(X2.w, X3.x), X3.y);
                        eR2 = fminf(fminf(w3, fminf(ru[12], rd[12])), fminf(rm_[12], rp_[12]));
                    }
                    hlo = vmax4(vmax4(make_float4(eL2, l2.x, l2.y, l2.z), l2),
                                make_float4(l2.y, l2.z, l2.w, g2.x));
                    hhi = vmax4(vmax4(make_float4(l2.w, g2.x, g2.y, g2.z), g2),
                                make_float4(g2.y, g2.z, g2.w, eR2));
                }
                float* hw = &srm[s & 1][mr2 * RSF + 8 * k2];
                *(float4*)hw       = hlo;
                *(float4*)(hw + 4) = hhi;
            }
        }

        int dm = s - 1;
        float4 xclo = INF4, xchi = INF4;
        if (dm >= gd0 && dm <= gd0 + CD - 1) {
            if (sv) { xclo = vM1; xchi = vM2; }
            else {
                const float* xd = sx[(dm + 4) & 3];
                xclo = *(const float4*)&xd[(r + 2) * XSF + 8 * k + 4];
                xchi = *(const float4*)&xd[(r + 2) * XSF + 8 * k + 8];
            }
        }

        float4 hclo = NINF4, hchi = NINF4;
        if (s >= gd0 && dm >= 0 && dm < D) {
            const float* m = srm[dm & 1];
            float4 a0 = *(const float4*)&m[r * RSF + 8 * k];
            float4 a1 = *(const float4*)&m[r * RSF + 8 * k + 4];
            float4 b0 = *(const float4*)&m[(r + 2) * RSF + 8 * k];
            float4 b1 = *(const float4*)&m[(r + 2) * RSF + 8 * k + 4];
            hclo = vmax4(vmax4(a0, rmplo), b0);
            hchi = vmax4(vmax4(a1, rmphi), b1);
        }

        int d = s - 2;
        if (d >= gd0 && d <= gd0 + CD - 1) {
            float4 mxlo = vmax4(h2lo, vmax4(h1lo, hclo));
            float4 mxhi = vmax4(h2hi, vmax4(h1hi, hchi));
            float4 rlo, rhi;
            rlo.x = fmaxf(xplo.x - (mxlo.x - p2lo.x), 0.0f);
            rlo.y = fmaxf(xplo.y - (mxlo.y - p2lo.y), 0.0f);
            rlo.z = fmaxf(xplo.z - (mxlo.z - p2lo.z), 0.0f);
            rlo.w = fmaxf(xplo.w - (mxlo.w - p2lo.w), 0.0f);
            rhi.x = fmaxf(xphi.x - (mxhi.x - p2hi.x), 0.0f);
            rhi.y = fmaxf(xphi.y - (mxhi.y - p2hi.y), 0.0f);
            rhi.z = fmaxf(xphi.z - (mxhi.z - p2hi.z), 0.0f);
            rhi.w = fmaxf(xphi.w - (mxhi.w - p2hi.w), 0.0f);
            long off = (long)d * HW + (h0 + r) * W + (w0 + 8 * k);
            float4 o1 = apply_mode(*(const float4*)(otA + off),     otB, off,     om);
            float4 o2 = apply_mode(*(const float4*)(otA + off + 4), otB, off + 4, om);
            s0 += (double)(rlo.x * o1.x) + (double)(rlo.y * o1.y)
                + (double)(rlo.z * o1.z) + (double)(rlo.w * o1.w)
                + (double)(rhi.x * o2.x) + (double)(rhi.y * o2.y)
                + (double)(rhi.z * o2.z) + (double)(rhi.w * o2.w);
            s1 += (double)rlo.x + (double)rlo.y + (double)rlo.z + (double)rlo.w
                + (double)rhi.x + (double)rhi.y + (double)rhi.z + (double)rhi.w;
        }

        h2lo = h1lo; h2hi = h1hi; h1lo = hclo; h1hi = hchi;
        p2lo = p1lo; p2hi = p1hi; p1lo = lo;   p1hi = hi;
        rmplo = rmlo; rmphi = rmhi;
        xplo = xclo;  xphi = xchi;

        if (s <= gd0 + 1) seg_barrier_v0();
        else              seg_barrier_v2();
    }

    for (int off = 32; off > 0; off >>= 1) {
        s0 += __shfl_down(s0, off, 64);
        s1 += __shfl_down(s1, off, 64);
    }
    if ((tid & 63) == 0) {
        atomicAdd(&accp[0], s0);
        atomicAdd(&accp[1], s1);
    }
}

__global__ void final_kernel(const double* __restrict__ acc, float* __restrict__ out) {
    double clrecall = (acc[0] + 1e-12) / (acc[1] + 1e-12);
    double clacc    = (acc[2] + 1e-12) / (acc[3] + 1e-12);
    double cldice   = 2.0 * clrecall * clacc / (clrecall + clacc + 1e-12);
    out[0] = (float)(1.0 - cldice);
}

extern "C" void kernel_launch(void* const* d_in, const int* in_sizes, int n_in,
                              void* d_out, int out_size, void* d_ws, size_t ws_size,
                              hipStream_t stream) {
    const float* logits = (const float*)d_in[0];
    const float* target = (const float*)d_in[1];
    const float* mask   = (const float*)d_in[2];
    float* out = (float*)d_out;

    // Workspace (floats): A0 | B0 | A1 | B1 | acc(4 doubles) | infbuf(16B)
    float* A0 = (float*)d_ws;
    float* B0 = A0 + NV;

    bool big = ws_size >= (size_t)4 * NV * 4 + 64;
    float* A1    = big ? (B0 + NV) : A0;
    float* B1    = big ? (A1 + NV) : B0;
    double* acc  = big ? (double*)(B1 + NV) : (double*)(B0 + NV);
    float* infb  = (float*)(acc + 4);

    hipMemsetAsync(acc, 0, 4 * sizeof(double), stream);
    hipMemsetAsync(infb, 0x7F, 16, stream);   // 0x7F7F7F7F = 3.39e38 (+INF-like)

    dim3 blk(256);

    if (big) {
        dim3 g(512);   // 2 tensors x 256 blocks; 2 blocks/CU, all resident
        // chain0: skel(target*mask); chain1: skel(sigmoid(logits)*mask)
        skel_first_kernel<<<g, blk, 0, stream>>>(target, mask, 1, A0,
                                                 logits, mask, 2, A1);
        skel_mid_kernel<<<g, blk, 0, stream>>>(A0, B0, A1, B1, infb);
        skel_mid_kernel<<<g, blk, 0, stream>>>(B0, A0, B1, A1, infb);
        skel_mid_kernel<<<g, blk, 0, stream>>>(A0, B0, A1, B1, infb);
        skel_final_kernel<<<g, blk, 0, stream>>>(B0, logits, mask, 2, acc,
                                                 B1, target, mask, 1, acc + 2, infb);
    } else {
        dim3 g(256);   // sequential fallback (t = 0 always)
        skel_first_kernel<<<g, blk, 0, stream>>>(target, mask, 1, A0,
                                                 target, mask, 1, A0);
        skel_mid_kernel<<<g, blk, 0, stream>>>(A0, B0, A0, B0, infb);
        skel_mid_kernel<<<g, blk, 0, stream>>>(B0, A0, B0, A0, infb);
        skel_mid_kernel<<<g, blk, 0, stream>>>(A0, B0, A0, B0, infb);
        skel_final_kernel<<<g, blk, 0, stream>>>(B0, logits, mask, 2, acc,
                                                 B0, logits, mask, 2, acc, infb);
        skel_first_kernel<<<g, blk, 0, stream>>>(logits, mask, 2, A0,
                                                 logits, mask, 2, A0);
        skel_mid_kernel<<<g, blk, 0, stream>>>(A0, B0, A0, B0, infb);
        skel_mid_kernel<<<g, blk, 0, stream>>>(B0, A0, B0, A0, infb);
        skel_mid_kernel<<<g, blk, 0, stream>>>(A0, B0, A0, B0, infb);
        skel_final_kernel<<<g, blk, 0, stream>>>(B0, target, mask, 1, acc + 2,
                                                 B0, target, mask, 1, acc + 2, infb);
    }

    final_kernel<<<1, 1, 0, stream>>>(acc, out);
}

// Round 19
// 277.519 us; speedup vs baseline: 1.1291x; 1.1291x over previous
//
#include <hip/hip_runtime.h>
#include <math.h>

// SoftclDiceLoss on (B,C,D,H,W) = (2,1,64,256,256) float32.
// R19 = R16 restored byte-for-byte (the 283us champion) + one trim: acc
// zeroing moved into prep_kernel (drops one hipMemsetAsync launch).
// Champion structure: CD=16, grid 512, x ring-4 staged via global_load_lds
// (linear-with-holes layout, XSF=76), srm ring-2, ONE barrier per segment
// with counted vmcnt drain (v0 lead-in / v2 steady), xc-dedup (x-center of
// plane s-1 == M1/M2 read by B(s)), merged tgt/pred chains, XCD swizzle.
// Falsified alternatives (do not retry): register carries (R12/R13, +VALU),
// prep-fold into skel (R14/R17/R18, fused staging loses more than prep
// costs), 3 blocks/CU via extra barrier or ring-3 (R11/R12, occupancy gain
// swamped), 2-phase srm single-buffer (R11).

constexpr int Bn = 2;
constexpr int D  = 64;
constexpr int H  = 256;
constexpr int W  = 256;
constexpr int HW = H * W;           // 65536
constexpr int NV = Bn * D * H * W;  // 8388608

constexpr int CD  = 16;             // D-chunk per block
constexpr int XSF = 76;             // x LDS row stride (19 quads, odd)
constexpr int XPQ = 768;            // padded plane size in quads (12 x 64)
constexpr int RSF = 68;             // rowmax LDS row stride (17 quads, odd)

__device__ __forceinline__ void seg_barrier_v0() {
    asm volatile("s_waitcnt vmcnt(0) lgkmcnt(0)" ::: "memory");
    __builtin_amdgcn_s_barrier();
    asm volatile("" ::: "memory");
}
__device__ __forceinline__ void seg_barrier_v2() {
    asm volatile("s_waitcnt vmcnt(2) lgkmcnt(0)" ::: "memory");
    __builtin_amdgcn_s_barrier();
    asm volatile("" ::: "memory");
}

__device__ __forceinline__ float4 vmin4(float4 a, float4 b) {
    return make_float4(fminf(a.x,b.x), fminf(a.y,b.y), fminf(a.z,b.z), fminf(a.w,b.w));
}
__device__ __forceinline__ float4 vmax4(float4 a, float4 b) {
    return make_float4(fmaxf(a.x,b.x), fmaxf(a.y,b.y), fmaxf(a.z,b.z), fmaxf(a.w,b.w));
}
__device__ __forceinline__ float4 sh1(float4 a, float4 b) { return make_float4(a.y,a.z,a.w,b.x); }
__device__ __forceinline__ float4 sh3(float4 a, float4 b) { return make_float4(a.w,b.x,b.y,b.z); }

__global__ __launch_bounds__(256) void prep_kernel(const float* __restrict__ logits,
                                                   const float* __restrict__ target,
                                                   const float* __restrict__ mask,
                                                   float* __restrict__ pred,
                                                   float* __restrict__ tgt,
                                                   float* __restrict__ infbuf,
                                                   double* __restrict__ acc) {
    int i = (blockIdx.x * 256 + threadIdx.x) * 4;
    float4 lg = *(const float4*)(logits + i);
    float4 tg = *(const float4*)(target + i);
    float4 mk = *(const float4*)(mask + i);
    float4 p, t;
    p.x = (1.0f/(1.0f+expf(-lg.x)))*mk.x;  t.x = tg.x*mk.x;
    p.y = (1.0f/(1.0f+expf(-lg.y)))*mk.y;  t.y = tg.y*mk.y;
    p.z = (1.0f/(1.0f+expf(-lg.z)))*mk.z;  t.z = tg.z*mk.z;
    p.w = (1.0f/(1.0f+expf(-lg.w)))*mk.w;  t.w = tg.w*mk.w;
    *(float4*)(pred + i) = p;
    *(float4*)(tgt + i)  = t;
    if (blockIdx.x == 0 && threadIdx.x == 0) {
        *(float4*)infbuf = make_float4(INFINITY, INFINITY, INFINITY, INFINITY);
        acc[0] = 0.0; acc[1] = 0.0; acc[2] = 0.0; acc[3] = 0.0;
    }
}

template <bool FINAL>
__global__ __launch_bounds__(256) void skel_iter_kernel(
        const float* __restrict__ in0, float* __restrict__ out0,
        const float* __restrict__ oth0, double* __restrict__ acc0,
        const float* __restrict__ in1, float* __restrict__ out1,
        const float* __restrict__ oth1, double* __restrict__ acc1,
        const float* __restrict__ infbuf) {
    __shared__ float sx[4][XPQ * 4];    // x ring of 4, padded planes (48 KB)
    __shared__ float srm[2][34 * RSF];  // rowmax ring of 2 (18.5 KB)

    // XCD-chunked swizzle
    int cpx = gridDim.x >> 3;
    int hwb = blockIdx.x;
    int bx  = (hwb & 7) * cpx + (hwb >> 3);

    int t   = bx >> 8;                 // tensor select (0 when grid=256)
    int bt  = bx & 255;
    int w0  = (bt & 3) * 64;
    int h0  = ((bt >> 2) & 7) * 32;
    int gd0 = ((bt >> 5) & 3) * CD;
    int b   = (bt >> 7) & 1;

    const float* xin  = t ? in1  : in0;
    float*       xout = t ? out1 : out0;
    const float* oth  = t ? oth1 : oth0;
    double*      accp = t ? acc1 : acc0;

    int tid  = threadIdx.x;
    int r    = tid >> 3;   // 0..31 output row
    int k    = tid & 7;    // 0..7  8-col job
    int wv   = tid >> 6;   // wave id 0..3
    int lane = tid & 63;

    const float* xb  = xin + b * (D * HW);
    float*       ob  = xout ? (xout + b * (D * HW)) : nullptr;
    const float* otb = oth + b * (D * HW);

    const float4 INF4  = make_float4( INFINITY,  INFINITY,  INFINITY,  INFINITY);
    const float4 NINF4 = make_float4(-INFINITY, -INFINITY, -INFINITY, -INFINITY);

    // Per-lane gload source precompute: chunk c = wv + 4*i, quad j = 64c+lane,
    // row = j/19, q = j%19. Holes (q==18), rows>=36, and OOB -> infbuf.
    int  offe[3];
    bool okl[3];
    for (int i = 0; i < 3; ++i) {
        int c = wv + 4 * i;
        int j = 64 * c + lane;
        int row = j / 19;
        int q = j - 19 * row;
        int gh = h0 - 2 + row;
        int gw = w0 - 4 + 4 * q;
        okl[i] = (q < 18) && (row < 36) &&
                 ((unsigned)gh < (unsigned)H) && ((unsigned)gw < (unsigned)W);
        offe[i] = gh * W + gw;
    }

    auto issue_g = [&](int p) {
        bool pok = (p >= 0 && p < D);
        const float* pbase = xb + (long)p * HW;
        float* slot = sx[(p + 4) & 3];
        #pragma unroll
        for (int i = 0; i < 3; ++i) {
            const float* src = (pok && okl[i]) ? (pbase + offe[i]) : infbuf;
            float* dst = slot + (wv + 4 * i) * 256;   // 64 quads = 256 floats
            __builtin_amdgcn_global_load_lds(
                (const __attribute__((address_space(1))) void*)src,
                (__attribute__((address_space(3))) void*)dst, 16, 0, 0);
        }
    };

    // Prologue: planes gd0-2..gd0+1 staged via DMA; full drain.
    issue_g(gd0 - 2); issue_g(gd0 - 1); issue_g(gd0); issue_g(gd0 + 1);
    __syncthreads();

    float4 h1lo=NINF4, h1hi=NINF4, h2lo=NINF4, h2hi=NINF4;  // hw9 D-ring
    float4 p1lo=NINF4, p1hi=NINF4, p2lo=NINF4, p2hi=NINF4;  // mp centers
    float4 rmplo=NINF4, rmphi=NINF4;                        // reg rowmax of s-1
    float4 xplo=INF4, xphi=INF4;                            // x center of s-2
    double s0 = 0.0, s1 = 0.0;

    for (int s = gd0 - 1; s <= gd0 + CD + 1; ++s) {
        // ---- staging: DMA plane s+2 into slot (s+2)&3 (depth-1) ----
        if (s >= gd0 && s + 2 <= gd0 + CD + 1) issue_g(s + 2);
        asm volatile("" ::: "memory");   // pin gloads before later VMEM ops

        // ---- B(s): mp row r+1 in regs, rowmax -> srm[s&1] ----
        bool sv = (s >= 0 && s < D && s <= gd0 + CD);
        float4 lo = NINF4, hi = NINF4, rmlo = NINF4, rmhi = NINF4;
        float4 vM1 = INF4, vM2 = INF4;   // saved M1/M2 (== xc of plane s-1)
        if (sv) {
            const float* xq = sx[(s + 4) & 3];
            const float* xm = sx[(s + 3) & 3];
            const float* xp = sx[(s + 5) & 3];
            {
                const float* rc  = &xq[(r + 2) * XSF + 8 * k];
                const float* ru  = &xq[(r + 1) * XSF + 8 * k];
                const float* rd  = &xq[(r + 3) * XSF + 8 * k];
                const float* rm_ = &xm[(r + 2) * XSF + 8 * k];
                const float* rp_ = &xp[(r + 2) * XSF + 8 * k];
                float4 X0 = *(const float4*)rc,        X1 = *(const float4*)(rc + 4),
                       X2 = *(const float4*)(rc + 8),  X3 = *(const float4*)(rc + 12);
                float4 U1 = *(const float4*)(ru + 4),  U2 = *(const float4*)(ru + 8);
                float4 Dn1= *(const float4*)(rd + 4),  Dn2= *(const float4*)(rd + 8);
                float4 M1 = *(const float4*)(rm_ + 4), M2 = *(const float4*)(rm_ + 8);
                float4 P1 = *(const float4*)(rp_ + 4), P2 = *(const float4*)(rp_ + 8);
                vM1 = M1; vM2 = M2;
                lo = vmin4(vmin4(sh3(X0, X1), X1), sh1(X1, X2));
                lo = vmin4(lo, vmin4(vmin4(U1, Dn1), vmin4(M1, P1)));
                hi = vmin4(vmin4(sh3(X1, X2), X2), sh1(X2, X3));
                hi = vmin4(hi, vmin4(vmin4(U2, Dn2), vmin4(M2, P2)));
                float eL = __shfl_up(hi.w, 1);
                float eR = __shfl_down(lo.x, 1);
                if (k == 0) {
                    eL = -INFINITY;
                    if (w0 > 0) {
                        float w3 = fminf(fminf(X0.z, X0.w), X1.x);
                        eL = fminf(fminf(w3, fminf(ru[3], rd[3])),
                                   fminf(rm_[3], rp_[3]));
                    }
                }
                if (k == 7) {
                    eR = -INFINITY;
                    if (w0 + 64 < W) {
                        float w3 = fminf(fminf(X2.w, X3.x), X3.y);
                        eR = fminf(fminf(w3, fminf(ru[12], rd[12])),
                                   fminf(rm_[12], rp_[12]));
                    }
                }
                rmlo = vmax4(vmax4(make_float4(eL, lo.x, lo.y, lo.z), lo),
                             make_float4(lo.y, lo.z, lo.w, hi.x));
                rmhi = vmax4(vmax4(make_float4(lo.w, hi.x, hi.y, hi.z), hi),
                             make_float4(hi.y, hi.z, hi.w, eR));
                float* rw = &srm[s & 1][(r + 1) * RSF + 8 * k];
                *(float4*)rw       = rmlo;
                *(float4*)(rw + 4) = rmhi;
            }
            if (tid < 16) {    // halo rows 0 and 33, fully in-thread
                int mr2 = (tid >> 3) ? 33 : 0;
                int k2  = tid & 7;
                int gh2 = h0 - 1 + mr2;
                float4 hlo = NINF4, hhi = NINF4;
                if ((unsigned)gh2 < (unsigned)H) {
                    int xr2 = mr2 + 1;
                    const float* rc  = &xq[xr2 * XSF + 8 * k2];
                    const float* ru  = &xq[(xr2 - 1) * XSF + 8 * k2];
                    const float* rd  = &xq[(xr2 + 1) * XSF + 8 * k2];
                    const float* rm_ = &xm[xr2 * XSF + 8 * k2];
                    const float* rp_ = &xp[xr2 * XSF + 8 * k2];
                    float4 X0 = *(const float4*)rc,        X1 = *(const float4*)(rc + 4),
                           X2 = *(const float4*)(rc + 8),  X3 = *(const float4*)(rc + 12);
                    float4 U1 = *(const float4*)(ru + 4),  U2 = *(const float4*)(ru + 8);
                    float4 Dn1= *(const float4*)(rd + 4),  Dn2= *(const float4*)(rd + 8);
                    float4 M1 = *(const float4*)(rm_ + 4), M2 = *(const float4*)(rm_ + 8);
                    float4 P1 = *(const float4*)(rp_ + 4), P2 = *(const float4*)(rp_ + 8);
                    float4 l2 = vmin4(vmin4(sh3(X0, X1), X1), sh1(X1, X2));
                    l2 = vmin4(l2, vmin4(vmin4(U1, Dn1), vmin4(M1, P1)));
                    float4 g2 = vmin4(vmin4(sh3(X1, X2), X2), sh1(X2, X3));
                    g2 = vmin4(g2, vmin4(vmin4(U2, Dn2), vmin4(M2, P2)));
                    float eL2 = -INFINITY, eR2 = -INFINITY;
                    if (w0 + 8 * k2 - 1 >= 0) {
                        float w3 = fminf(fminf(X0.z, X0.w), X1.x);
                        eL2 = fminf(fminf(w3, fminf(ru[3], rd[3])),
                                    fminf(rm_[3], rp_[3]));
                    }
                    if (w0 + 8 * k2 + 8 < W) {
                        float w3 = fminf(fminf(X2.w, X3.x), X3.y);
                        eR2 = fminf(fminf(w3, fminf(ru[12], rd[12])),
                                    fminf(rm_[12], rp_[12]));
                    }
                    hlo = vmax4(vmax4(make_float4(eL2, l2.x, l2.y, l2.z), l2),
                                make_float4(l2.y, l2.z, l2.w, g2.x));
                    hhi = vmax4(vmax4(make_float4(l2.w, g2.x, g2.y, g2.z), g2),
                                make_float4(g2.y, g2.z, g2.w, eR2));
                }
                float* hw = &srm[s & 1][mr2 * RSF + 8 * k2];
                *(float4*)hw       = hlo;
                *(float4*)(hw + 4) = hhi;
            }
        }

        // ---- xc: x center of plane s-1 == vM1/vM2 (xc-dedup) ----
        int dm = s - 1;
        float4 xclo = INF4, xchi = INF4;
        if (dm >= gd0 && dm <= gd0 + CD - 1) {
            if (sv) { xclo = vM1; xchi = vM2; }
            else {   // only the s == gd0+CD == D case (last chunk)
                const float* xd = sx[(dm + 4) & 3];
                xclo = *(const float4*)&xd[(r + 2) * XSF + 8 * k + 4];
                xchi = *(const float4*)&xd[(r + 2) * XSF + 8 * k + 8];
            }
        }

        // ---- H(s-1): hw9 of plane s-1 (rm written last segment + reg row) ----
        float4 hclo = NINF4, hchi = NINF4;
        if (s >= gd0 && dm >= 0 && dm < D) {
            const float* m = srm[dm & 1];
            float4 a0 = *(const float4*)&m[r * RSF + 8 * k];
            float4 a1 = *(const float4*)&m[r * RSF + 8 * k + 4];
            float4 b0 = *(const float4*)&m[(r + 2) * RSF + 8 * k];
            float4 b1 = *(const float4*)&m[(r + 2) * RSF + 8 * k + 4];
            hclo = vmax4(vmax4(a0, rmplo), b0);
            hchi = vmax4(vmax4(a1, rmphi), b1);
        }

        // ---- C(s-2): output d = s-2 (registers only + global) ----
        int d = s - 2;
        if (d >= gd0 && d <= gd0 + CD - 1) {
            float4 mxlo = vmax4(h2lo, vmax4(h1lo, hclo));
            float4 mxhi = vmax4(h2hi, vmax4(h1hi, hchi));
            float4 rlo, rhi;
            rlo.x = fmaxf(xplo.x - (mxlo.x - p2lo.x), 0.0f);
            rlo.y = fmaxf(xplo.y - (mxlo.y - p2lo.y), 0.0f);
            rlo.z = fmaxf(xplo.z - (mxlo.z - p2lo.z), 0.0f);
            rlo.w = fmaxf(xplo.w - (mxlo.w - p2lo.w), 0.0f);
            rhi.x = fmaxf(xphi.x - (mxhi.x - p2hi.x), 0.0f);
            rhi.y = fmaxf(xphi.y - (mxhi.y - p2hi.y), 0.0f);
            rhi.z = fmaxf(xphi.z - (mxhi.z - p2hi.z), 0.0f);
            rhi.w = fmaxf(xphi.w - (mxhi.w - p2hi.w), 0.0f);
            long off = (long)d * HW + (h0 + r) * W + (w0 + 8 * k);
            if constexpr (FINAL) {
                float4 o1 = *(const float4*)(otb + off);
                float4 o2 = *(const float4*)(otb + off + 4);
                s0 += (double)(rlo.x * o1.x) + (double)(rlo.y * o1.y)
                    + (double)(rlo.z * o1.z) + (double)(rlo.w * o1.w)
                    + (double)(rhi.x * o2.x) + (double)(rhi.y * o2.y)
                    + (double)(rhi.z * o2.z) + (double)(rhi.w * o2.w);
                s1 += (double)rlo.x + (double)rlo.y + (double)rlo.z + (double)rlo.w
                    + (double)rhi.x + (double)rhi.y + (double)rhi.z + (double)rhi.w;
            } else {
                *(float4*)(ob + off)     = rlo;
                *(float4*)(ob + off + 4) = rhi;
            }
        }

        // ---- shifts ----
        h2lo = h1lo; h2hi = h1hi; h1lo = hclo; h1hi = hchi;
        p2lo = p1lo; p2hi = p1hi; p1lo = lo;   p1hi = hi;
        rmplo = rmlo; rmphi = rmhi;
        xplo = xclo;  xphi = xchi;

        // ---- barrier: drain gloads (v0 while no stores exist, else v2) ----
        if (s <= gd0 + 1) seg_barrier_v0();
        else              seg_barrier_v2();
    }

    if constexpr (FINAL) {
        for (int off = 32; off > 0; off >>= 1) {
            s0 += __shfl_down(s0, off, 64);
            s1 += __shfl_down(s1, off, 64);
        }
        if ((tid & 63) == 0) {
            atomicAdd(&accp[0], s0);
            atomicAdd(&accp[1], s1);
        }
    }
}

__global__ void final_kernel(const double* __restrict__ acc, float* __restrict__ out) {
    double clrecall = (acc[0] + 1e-12) / (acc[1] + 1e-12);
    double clacc    = (acc[2] + 1e-12) / (acc[3] + 1e-12);
    double cldice   = 2.0 * clrecall * clacc / (clrecall + clacc + 1e-12);
    out[0] = (float)(1.0 - cldice);
}

extern "C" void kernel_launch(void* const* d_in, const int* in_sizes, int n_in,
                              void* d_out, int out_size, void* d_ws, size_t ws_size,
                              hipStream_t stream) {
    const float* logits = (const float*)d_in[0];
    const float* target = (const float*)d_in[1];
    const float* mask   = (const float*)d_in[2];
    float* out = (float*)d_out;

    float* pred = (float*)d_ws;
    float* tgt  = pred + NV;
    float* A0   = tgt + NV;
    float* B0   = A0 + NV;

    bool big = ws_size >= (size_t)6 * NV * 4 + 64;
    float* A1    = big ? (B0 + NV) : A0;
    float* B1    = big ? (A1 + NV) : B0;
    double* acc  = big ? (double*)(B1 + NV) : (double*)(B0 + NV);
    float* infb  = (float*)(acc + 4);   // 16B +INF dummy for OOB gload lanes

    dim3 blk(256);
    prep_kernel<<<dim3(NV / 1024), blk, 0, stream>>>(logits, target, mask, pred, tgt,
                                                     infb, acc);

    if (big) {
        dim3 g(512);   // 2 tensors x 256 blocks; 2 blocks/CU, all resident
        skel_iter_kernel<false><<<g, blk, 0, stream>>>(tgt, A0, pred, acc, pred, A1, tgt, acc + 2, infb);
        skel_iter_kernel<false><<<g, blk, 0, stream>>>(A0, B0, pred, acc, A1, B1, tgt, acc + 2, infb);
        skel_iter_kernel<false><<<g, blk, 0, stream>>>(B0, A0, pred, acc, B1, A1, tgt, acc + 2, infb);
        skel_iter_kernel<false><<<g, blk, 0, stream>>>(A0, B0, pred, acc, A1, B1, tgt, acc + 2, infb);
        skel_iter_kernel<true ><<<g, blk, 0, stream>>>(B0, nullptr, pred, acc, B1, nullptr, tgt, acc + 2, infb);
    } else {
        dim3 g(256);   // sequential fallback (t = 0 always)
        skel_iter_kernel<false><<<g, blk, 0, stream>>>(tgt, A0, pred, acc, tgt, A0, pred, acc, infb);
        skel_iter_kernel<false><<<g, blk, 0, stream>>>(A0, B0, pred, acc, A0, B0, pred, acc, infb);
        skel_iter_kernel<false><<<g, blk, 0, stream>>>(B0, A0, pred, acc, B0, A0, pred, acc, infb);
        skel_iter_kernel<false><<<g, blk, 0, stream>>>(A0, B0, pred, acc, A0, B0, pred, acc, infb);
        skel_iter_kernel<true ><<<g, blk, 0, stream>>>(B0, nullptr, pred, acc, B0, nullptr, pred, acc, infb);
        skel_iter_kernel<false><<<g, blk, 0, stream>>>(pred, A0, tgt, acc + 2, pred, A0, tgt, acc + 2, infb);
        skel_iter_kernel<false><<<g, blk, 0, stream>>>(A0, B0, tgt, acc + 2, A0, B0, tgt, acc + 2, infb);
        skel_iter_kernel<false><<<g, blk, 0, stream>>>(B0, A0, tgt, acc + 2, B0, A0, tgt, acc + 2, infb);
        skel_iter_kernel<false><<<g, blk, 0, stream>>>(A0, B0, tgt, acc + 2, A0, B0, tgt, acc + 2, infb);
        skel_iter_kernel<true ><<<g, blk, 0, stream>>>(B0, nullptr, tgt, acc + 2, B0, nullptr, tgt, acc + 2, infb);
    }

    final_kernel<<<1, 1, 0, stream>>>(acc, out);
}

// Round 20
// 275.812 us; speedup vs baseline: 1.1361x; 1.0062x over previous
//
#include <hip/hip_runtime.h>
#include <math.h>

// SoftclDiceLoss on (B,C,D,H,W) = (2,1,64,256,256) float32.
// R20 = R19 (277.5us champion) + X0/X3-elimination in cross-min:
//   X0.w(k) == X2.w(k-1), X3.x(k) == X1.x(k+1)  (lane-adjacent within row)
//   -> replace the X0 and X3 ds_read_b128 with __shfl_up/__shfl_down,
//   patch k==0/7 lanes with one scalar b32 each (edge values are staged INF
//   so semantics are exact). W-edge branches read their X0.z/X3.y as scalars.
// Champion structure (unchanged): CD=16, grid 512, x ring-4 DMA staging via
// global_load_lds (linear-with-holes, XSF=76), srm ring-2, ONE barrier/seg
// with counted vmcnt (v0 lead-in / v2 steady), xc-dedup, merged chains,
// XCD swizzle, acc zero in prep.
// Falsified (do not retry): register carries (R12/R13), prep-fold
// (R14/R17/R18), 3 blocks/CU (R11/R12), srm single-buffer (R11).

constexpr int Bn = 2;
constexpr int D  = 64;
constexpr int H  = 256;
constexpr int W  = 256;
constexpr int HW = H * W;           // 65536
constexpr int NV = Bn * D * H * W;  // 8388608

constexpr int CD  = 16;             // D-chunk per block
constexpr int XSF = 76;             // x LDS row stride (19 quads, odd)
constexpr int XPQ = 768;            // padded plane size in quads (12 x 64)
constexpr int RSF = 68;             // rowmax LDS row stride (17 quads, odd)

__device__ __forceinline__ void seg_barrier_v0() {
    asm volatile("s_waitcnt vmcnt(0) lgkmcnt(0)" ::: "memory");
    __builtin_amdgcn_s_barrier();
    asm volatile("" ::: "memory");
}
__device__ __forceinline__ void seg_barrier_v2() {
    asm volatile("s_waitcnt vmcnt(2) lgkmcnt(0)" ::: "memory");
    __builtin_amdgcn_s_barrier();
    asm volatile("" ::: "memory");
}

__device__ __forceinline__ float4 vmin4(float4 a, float4 b) {
    return make_float4(fminf(a.x,b.x), fminf(a.y,b.y), fminf(a.z,b.z), fminf(a.w,b.w));
}
__device__ __forceinline__ float4 vmax4(float4 a, float4 b) {
    return make_float4(fmaxf(a.x,b.x), fmaxf(a.y,b.y), fmaxf(a.z,b.z), fmaxf(a.w,b.w));
}
__device__ __forceinline__ float4 sh1(float4 a, float4 b) { return make_float4(a.y,a.z,a.w,b.x); }

__global__ __launch_bounds__(256) void prep_kernel(const float* __restrict__ logits,
                                                   const float* __restrict__ target,
                                                   const float* __restrict__ mask,
                                                   float* __restrict__ pred,
                                                   float* __restrict__ tgt,
                                                   float* __restrict__ infbuf,
                                                   double* __restrict__ acc) {
    int i = (blockIdx.x * 256 + threadIdx.x) * 4;
    float4 lg = *(const float4*)(logits + i);
    float4 tg = *(const float4*)(target + i);
    float4 mk = *(const float4*)(mask + i);
    float4 p, t;
    p.x = (1.0f/(1.0f+expf(-lg.x)))*mk.x;  t.x = tg.x*mk.x;
    p.y = (1.0f/(1.0f+expf(-lg.y)))*mk.y;  t.y = tg.y*mk.y;
    p.z = (1.0f/(1.0f+expf(-lg.z)))*mk.z;  t.z = tg.z*mk.z;
    p.w = (1.0f/(1.0f+expf(-lg.w)))*mk.w;  t.w = tg.w*mk.w;
    *(float4*)(pred + i) = p;
    *(float4*)(tgt + i)  = t;
    if (blockIdx.x == 0 && threadIdx.x == 0) {
        *(float4*)infbuf = make_float4(INFINITY, INFINITY, INFINITY, INFINITY);
        acc[0] = 0.0; acc[1] = 0.0; acc[2] = 0.0; acc[3] = 0.0;
    }
}

template <bool FINAL>
__global__ __launch_bounds__(256) void skel_iter_kernel(
        const float* __restrict__ in0, float* __restrict__ out0,
        const float* __restrict__ oth0, double* __restrict__ acc0,
        const float* __restrict__ in1, float* __restrict__ out1,
        const float* __restrict__ oth1, double* __restrict__ acc1,
        const float* __restrict__ infbuf) {
    __shared__ float sx[4][XPQ * 4];    // x ring of 4, padded planes (48 KB)
    __shared__ float srm[2][34 * RSF];  // rowmax ring of 2 (18.5 KB)

    // XCD-chunked swizzle
    int cpx = gridDim.x >> 3;
    int hwb = blockIdx.x;
    int bx  = (hwb & 7) * cpx + (hwb >> 3);

    int t   = bx >> 8;                 // tensor select (0 when grid=256)
    int bt  = bx & 255;
    int w0  = (bt & 3) * 64;
    int h0  = ((bt >> 2) & 7) * 32;
    int gd0 = ((bt >> 5) & 3) * CD;
    int b   = (bt >> 7) & 1;

    const float* xin  = t ? in1  : in0;
    float*       xout = t ? out1 : out0;
    const float* oth  = t ? oth1 : oth0;
    double*      accp = t ? acc1 : acc0;

    int tid  = threadIdx.x;
    int r    = tid >> 3;   // 0..31 output row
    int k    = tid & 7;    // 0..7  8-col job
    int wv   = tid >> 6;   // wave id 0..3
    int lane = tid & 63;

    const float* xb  = xin + b * (D * HW);
    float*       ob  = xout ? (xout + b * (D * HW)) : nullptr;
    const float* otb = oth + b * (D * HW);

    const float4 INF4  = make_float4( INFINITY,  INFINITY,  INFINITY,  INFINITY);
    const float4 NINF4 = make_float4(-INFINITY, -INFINITY, -INFINITY, -INFINITY);

    // Per-lane gload source precompute: chunk c = wv + 4*i, quad j = 64c+lane,
    // row = j/19, q = j%19. Holes (q==18), rows>=36, and OOB -> infbuf.
    int  offe[3];
    bool okl[3];
    for (int i = 0; i < 3; ++i) {
        int c = wv + 4 * i;
        int j = 64 * c + lane;
        int row = j / 19;
        int q = j - 19 * row;
        int gh = h0 - 2 + row;
        int gw = w0 - 4 + 4 * q;
        okl[i] = (q < 18) && (row < 36) &&
                 ((unsigned)gh < (unsigned)H) && ((unsigned)gw < (unsigned)W);
        offe[i] = gh * W + gw;
    }

    auto issue_g = [&](int p) {
        bool pok = (p >= 0 && p < D);
        const float* pbase = xb + (long)p * HW;
        float* slot = sx[(p + 4) & 3];
        #pragma unroll
        for (int i = 0; i < 3; ++i) {
            const float* src = (pok && okl[i]) ? (pbase + offe[i]) : infbuf;
            float* dst = slot + (wv + 4 * i) * 256;   // 64 quads = 256 floats
            __builtin_amdgcn_global_load_lds(
                (const __attribute__((address_space(1))) void*)src,
                (__attribute__((address_space(3))) void*)dst, 16, 0, 0);
        }
    };

    // Prologue: planes gd0-2..gd0+1 staged via DMA; full drain.
    issue_g(gd0 - 2); issue_g(gd0 - 1); issue_g(gd0); issue_g(gd0 + 1);
    __syncthreads();

    float4 h1lo=NINF4, h1hi=NINF4, h2lo=NINF4, h2hi=NINF4;  // hw9 D-ring
    float4 p1lo=NINF4, p1hi=NINF4, p2lo=NINF4, p2hi=NINF4;  // mp centers
    float4 rmplo=NINF4, rmphi=NINF4;                        // reg rowmax of s-1
    float4 xplo=INF4, xphi=INF4;                            // x center of s-2
    double s0 = 0.0, s1 = 0.0;

    for (int s = gd0 - 1; s <= gd0 + CD + 1; ++s) {
        // ---- staging: DMA plane s+2 into slot (s+2)&3 (depth-1) ----
        if (s >= gd0 && s + 2 <= gd0 + CD + 1) issue_g(s + 2);
        asm volatile("" ::: "memory");   // pin gloads before later VMEM ops

        // ---- B(s): mp row r+1 in regs, rowmax -> srm[s&1] ----
        bool sv = (s >= 0 && s < D && s <= gd0 + CD);
        float4 lo = NINF4, hi = NINF4, rmlo = NINF4, rmhi = NINF4;
        float4 vM1 = INF4, vM2 = INF4;   // saved M1/M2 (== xc of plane s-1)
        if (sv) {
            const float* xq = sx[(s + 4) & 3];
            const float* xm = sx[(s + 3) & 3];
            const float* xp = sx[(s + 5) & 3];
            {
                const float* rc  = &xq[(r + 2) * XSF + 8 * k];
                const float* ru  = &xq[(r + 1) * XSF + 8 * k];
                const float* rd  = &xq[(r + 3) * XSF + 8 * k];
                const float* rm_ = &xm[(r + 2) * XSF + 8 * k];
                const float* rp_ = &xp[(r + 2) * XSF + 8 * k];
                float4 X1 = *(const float4*)(rc + 4),  X2 = *(const float4*)(rc + 8);
                float4 U1 = *(const float4*)(ru + 4),  U2 = *(const float4*)(ru + 8);
                float4 Dn1= *(const float4*)(rd + 4),  Dn2= *(const float4*)(rd + 8);
                float4 M1 = *(const float4*)(rm_ + 4), M2 = *(const float4*)(rm_ + 8);
                float4 P1 = *(const float4*)(rp_ + 4), P2 = *(const float4*)(rp_ + 8);
                vM1 = M1; vM2 = M2;
                // X0.w / X3.x via lane shuffles (k==0/7 patched from LDS;
                // edge-staged values are INF so semantics are exact)
                float x0w = __shfl_up(X2.w, 1);
                float x3x = __shfl_down(X1.x, 1);
                if (k == 0) x0w = rc[3];
                if (k == 7) x3x = rc[12];
                lo = vmin4(vmin4(make_float4(x0w, X1.x, X1.y, X1.z), X1), sh1(X1, X2));
                lo = vmin4(lo, vmin4(vmin4(U1, Dn1), vmin4(M1, P1)));
                hi = vmin4(vmin4(sh1(X1, X2), X2), make_float4(X2.y, X2.z, X2.w, x3x));
                // NOTE: hi's left-neighbor vector is (X1.w, X2.x, X2.y, X2.z)
                hi = vmin4(make_float4(X1.w, X2.x, X2.y, X2.z),
                           vmin4(vmin4(X2, make_float4(X2.y, X2.z, X2.w, x3x)),
                                 vmin4(vmin4(U2, Dn2), vmin4(M2, P2))));
                float eL = __shfl_up(hi.w, 1);
                float eR = __shfl_down(lo.x, 1);
                if (k == 0) {
                    eL = -INFINITY;
                    if (w0 > 0) {
                        float w3 = fminf(fminf(rc[2], x0w), X1.x);
                        eL = fminf(fminf(w3, fminf(ru[3], rd[3])),
                                   fminf(rm_[3], rp_[3]));
                    }
                }
                if (k == 7) {
                    eR = -INFINITY;
                    if (w0 + 64 < W) {
                        float w3 = fminf(fminf(X2.w, x3x), rc[13]);
                        eR = fminf(fminf(w3, fminf(ru[12], rd[12])),
                                   fminf(rm_[12], rp_[12]));
                    }
                }
                rmlo = vmax4(vmax4(make_float4(eL, lo.x, lo.y, lo.z), lo),
                             make_float4(lo.y, lo.z, lo.w, hi.x));
                rmhi = vmax4(vmax4(make_float4(lo.w, hi.x, hi.y, hi.z), hi),
                             make_float4(hi.y, hi.z, hi.w, eR));
                float* rw = &srm[s & 1][(r + 1) * RSF + 8 * k];
                *(float4*)rw       = rmlo;
                *(float4*)(rw + 4) = rmhi;
            }
            if (tid < 16) {    // halo rows 0 and 33, fully in-thread
                int mr2 = (tid >> 3) ? 33 : 0;
                int k2  = tid & 7;
                int gh2 = h0 - 1 + mr2;
                // reads issued unconditionally (addresses valid), row-valid
                // gating applied after (matches R19 semantics)
                int xr2 = mr2 + 1;
                const float* rc  = &xq[xr2 * XSF + 8 * k2];
                const float* ru  = &xq[(xr2 - 1) * XSF + 8 * k2];
                const float* rd  = &xq[(xr2 + 1) * XSF + 8 * k2];
                const float* rm_ = &xm[xr2 * XSF + 8 * k2];
                const float* rp_ = &xp[xr2 * XSF + 8 * k2];
                float4 X1 = *(const float4*)(rc + 4),  X2 = *(const float4*)(rc + 8);
                float4 U1 = *(const float4*)(ru + 4),  U2 = *(const float4*)(ru + 8);
                float4 Dn1= *(const float4*)(rd + 4),  Dn2= *(const float4*)(rd + 8);
                float4 M1 = *(const float4*)(rm_ + 4), M2 = *(const float4*)(rm_ + 8);
                float4 P1 = *(const float4*)(rp_ + 4), P2 = *(const float4*)(rp_ + 8);
                float x0w = __shfl_up(X2.w, 1);
                float x3x = __shfl_down(X1.x, 1);
                if (k2 == 0) x0w = rc[3];
                if (k2 == 7) x3x = rc[12];
                float4 hlo = NINF4, hhi = NINF4;
                if ((unsigned)gh2 < (unsigned)H) {
                    float4 l2 = vmin4(vmin4(make_float4(x0w, X1.x, X1.y, X1.z), X1),
                                      sh1(X1, X2));
                    l2 = vmin4(l2, vmin4(vmin4(U1, Dn1), vmin4(M1, P1)));
                    float4 g2 = vmin4(make_float4(X1.w, X2.x, X2.y, X2.z),
                                      vmin4(vmin4(X2, make_float4(X2.y, X2.z, X2.w, x3x)),
                                            vmin4(vmin4(U2, Dn2), vmin4(M2, P2))));
                    float eL2 = -INFINITY, eR2 = -INFINITY;
                    if (w0 + 8 * k2 - 1 >= 0) {
                        float w3 = fminf(fminf(rc[2], x0w), X1.x);
                        eL2 = fminf(fminf(w3, fminf(ru[3], rd[3])),
                                    fminf(rm_[3], rp_[3]));
                    }
                    if (w0 + 8 * k2 + 8 < W) {
                        float w3 = fminf(fminf(X2.w, x3x), rc[13]);
                        eR2 = fminf(fminf(w3, fminf(ru[12], rd[12])),
                                    fminf(rm_[12], rp_[12]));
                    }
                    hlo = vmax4(vmax4(make_float4(eL2, l2.x, l2.y, l2.z), l2),
                                make_float4(l2.y, l2.z, l2.w, g2.x));
                    hhi = vmax4(vmax4(make_float4(l2.w, g2.x, g2.y, g2.z), g2),
                                make_float4(g2.y, g2.z, g2.w, eR2));
                }
                float* hw = &srm[s & 1][mr2 * RSF + 8 * k2];
                *(float4*)hw       = hlo;
                *(float4*)(hw + 4) = hhi;
            }
        }

        // ---- xc: x center of plane s-1 == vM1/vM2 (xc-dedup) ----
        int dm = s - 1;
        float4 xclo = INF4, xchi = INF4;
        if (dm >= gd0 && dm <= gd0 + CD - 1) {
            if (sv) { xclo = vM1; xchi = vM2; }
            else {   // only the s == gd0+CD == D case (last chunk)
                const float* xd = sx[(dm + 4) & 3];
                xclo = *(const float4*)&xd[(r + 2) * XSF + 8 * k + 4];
                xchi = *(const float4*)&xd[(r + 2) * XSF + 8 * k + 8];
            }
        }

        // ---- H(s-1): hw9 of plane s-1 (rm written last segment + reg row) ----
        float4 hclo = NINF4, hchi = NINF4;
        if (s >= gd0 && dm >= 0 && dm < D) {
            const float* m = srm[dm & 1];
            float4 a0 = *(const float4*)&m[r * RSF + 8 * k];
            float4 a1 = *(const float4*)&m[r * RSF + 8 * k + 4];
            float4 b0 = *(const float4*)&m[(r + 2) * RSF + 8 * k];
            float4 b1 = *(const float4*)&m[(r + 2) * RSF + 8 * k + 4];
            hclo = vmax4(vmax4(a0, rmplo), b0);
            hchi = vmax4(vmax4(a1, rmphi), b1);
        }

        // ---- C(s-2): output d = s-2 (registers only + global) ----
        int d = s - 2;
        if (d >= gd0 && d <= gd0 + CD - 1) {
            float4 mxlo = vmax4(h2lo, vmax4(h1lo, hclo));
            float4 mxhi = vmax4(h2hi, vmax4(h1hi, hchi));
            float4 rlo, rhi;
            rlo.x = fmaxf(xplo.x - (mxlo.x - p2lo.x), 0.0f);
            rlo.y = fmaxf(xplo.y - (mxlo.y - p2lo.y), 0.0f);
            rlo.z = fmaxf(xplo.z - (mxlo.z - p2lo.z), 0.0f);
            rlo.w = fmaxf(xplo.w - (mxlo.w - p2lo.w), 0.0f);
            rhi.x = fmaxf(xphi.x - (mxhi.x - p2hi.x), 0.0f);
            rhi.y = fmaxf(xphi.y - (mxhi.y - p2hi.y), 0.0f);
            rhi.z = fmaxf(xphi.z - (mxhi.z - p2hi.z), 0.0f);
            rhi.w = fmaxf(xphi.w - (mxhi.w - p2hi.w), 0.0f);
            long off = (long)d * HW + (h0 + r) * W + (w0 + 8 * k);
            if constexpr (FINAL) {
                float4 o1 = *(const float4*)(otb + off);
                float4 o2 = *(const float4*)(otb + off + 4);
                s0 += (double)(rlo.x * o1.x) + (double)(rlo.y * o1.y)
                    + (double)(rlo.z * o1.z) + (double)(rlo.w * o1.w)
                    + (double)(rhi.x * o2.x) + (double)(rhi.y * o2.y)
                    + (double)(rhi.z * o2.z) + (double)(rhi.w * o2.w);
                s1 += (double)rlo.x + (double)rlo.y + (double)rlo.z + (double)rlo.w
                    + (double)rhi.x + (double)rhi.y + (double)rhi.z + (double)rhi.w;
            } else {
                *(float4*)(ob + off)     = rlo;
                *(float4*)(ob + off + 4) = rhi;
            }
        }

        // ---- shifts ----
        h2lo = h1lo; h2hi = h1hi; h1lo = hclo; h1hi = hchi;
        p2lo = p1lo; p2hi = p1hi; p1lo = lo;   p1hi = hi;
        rmplo = rmlo; rmphi = rmhi;
        xplo = xclo;  xphi = xchi;

        // ---- barrier: drain gloads (v0 while no stores exist, else v2) ----
        if (s <= gd0 + 1) seg_barrier_v0();
        else              seg_barrier_v2();
    }

    if constexpr (FINAL) {
        for (int off = 32; off > 0; off >>= 1) {
            s0 += __shfl_down(s0, off, 64);
            s1 += __shfl_down(s1, off, 64);
        }
        if ((tid & 63) == 0) {
            atomicAdd(&accp[0], s0);
            atomicAdd(&accp[1], s1);
        }
    }
}

__global__ void final_kernel(const double* __restrict__ acc, float* __restrict__ out) {
    double clrecall = (acc[0] + 1e-12) / (acc[1] + 1e-12);
    double clacc    = (acc[2] + 1e-12) / (acc[3] + 1e-12);
    double cldice   = 2.0 * clrecall * clacc / (clrecall + clacc + 1e-12);
    out[0] = (float)(1.0 - cldice);
}

extern "C" void kernel_launch(void* const* d_in, const int* in_sizes, int n_in,
                              void* d_out, int out_size, void* d_ws, size_t ws_size,
                              hipStream_t stream) {
    const float* logits = (const float*)d_in[0];
    const float* target = (const float*)d_in[1];
    const float* mask   = (const float*)d_in[2];
    float* out = (float*)d_out;

    float* pred = (float*)d_ws;
    float* tgt  = pred + NV;
    float* A0   = tgt + NV;
    float* B0   = A0 + NV;

    bool big = ws_size >= (size_t)6 * NV * 4 + 64;
    float* A1    = big ? (B0 + NV) : A0;
    float* B1    = big ? (A1 + NV) : B0;
    double* acc  = big ? (double*)(B1 + NV) : (double*)(B0 + NV);
    float* infb  = (float*)(acc + 4);   // 16B +INF dummy for OOB gload lanes

    dim3 blk(256);
    prep_kernel<<<dim3(NV / 1024), blk, 0, stream>>>(logits, target, mask, pred, tgt,
                                                     infb, acc);

    if (big) {
        dim3 g(512);   // 2 tensors x 256 blocks; 2 blocks/CU, all resident
        skel_iter_kernel<false><<<g, blk, 0, stream>>>(tgt, A0, pred, acc, pred, A1, tgt, acc + 2, infb);
        skel_iter_kernel<false><<<g, blk, 0, stream>>>(A0, B0, pred, acc, A1, B1, tgt, acc + 2, infb);
        skel_iter_kernel<false><<<g, blk, 0, stream>>>(B0, A0, pred, acc, B1, A1, tgt, acc + 2, infb);
        skel_iter_kernel<false><<<g, blk, 0, stream>>>(A0, B0, pred, acc, A1, B1, tgt, acc + 2, infb);
        skel_iter_kernel<true ><<<g, blk, 0, stream>>>(B0, nullptr, pred, acc, B1, nullptr, tgt, acc + 2, infb);
    } else {
        dim3 g(256);   // sequential fallback (t = 0 always)
        skel_iter_kernel<false><<<g, blk, 0, stream>>>(tgt, A0, pred, acc, tgt, A0, pred, acc, infb);
        skel_iter_kernel<false><<<g, blk, 0, stream>>>(A0, B0, pred, acc, A0, B0, pred, acc, infb);
        skel_iter_kernel<false><<<g, blk, 0, stream>>>(B0, A0, pred, acc, B0, A0, pred, acc, infb);
        skel_iter_kernel<false><<<g, blk, 0, stream>>>(A0, B0, pred, acc, A0, B0, pred, acc, infb);
        skel_iter_kernel<true ><<<g, blk, 0, stream>>>(B0, nullptr, pred, acc, B0, nullptr, pred, acc, infb);
        skel_iter_kernel<false><<<g, blk, 0, stream>>>(pred, A0, tgt, acc + 2, pred, A0, tgt, acc + 2, infb);
        skel_iter_kernel<false><<<g, blk, 0, stream>>>(A0, B0, tgt, acc + 2, A0, B0, tgt, acc + 2, infb);
        skel_iter_kernel<false><<<g, blk, 0, stream>>>(B0, A0, tgt, acc + 2, B0, A0, tgt, acc + 2, infb);
        skel_iter_kernel<false><<<g, blk, 0, stream>>>(A0, B0, tgt, acc + 2, A0, B0, tgt, acc + 2, infb);
        skel_iter_kernel<true ><<<g, blk, 0, stream>>>(B0, nullptr, tgt, acc + 2, B0, nullptr, tgt, acc + 2, infb);
    }

    final_kernel<<<1, 1, 0, stream>>>(acc, out);
}